// Round 10
// baseline (556.544 us; speedup 1.0000x reference)
//
#include <hip/hip_runtime.h>
#include <hip/hip_bf16.h>
#include <hip/hip_fp16.h>
#include <type_traits>

// ---------------------------------------------------------------------------
// 2-layer GCN. CSR-gather aggregation (fp16 features, fp32 accum, 8x-unrolled
// edge loop for memory-level parallelism, (col,val) packed as int2).
// GEMMs: fp16 MFMA (fp32 accumulate), global_load_lds double-buffered staging
// with counted vmcnt(3) + raw s_barrier.
// ---------------------------------------------------------------------------

typedef _Float16 f16x8 __attribute__((ext_vector_type(8)));
typedef float f32x4 __attribute__((ext_vector_type(4)));

__device__ inline void async_copy16(const void* g, void* l) {
    __builtin_amdgcn_global_load_lds(
        (const __attribute__((address_space(1))) void*)g,
        (__attribute__((address_space(3))) void*)l, 16, 0, 0);
}

// ------------------------- graph preprocessing -----------------------------

__global__ __launch_bounds__(256) void init_node(float* deg, int* counts, int* fillc, int N) {
    int i = blockIdx.x * 256 + threadIdx.x;
    if (i < N) { deg[i] = 1.0f; counts[i] = 0; fillc[i] = 0; }
}

__global__ __launch_bounds__(256) void accum_deg_hist(const int* __restrict__ dst,
                                                      const float* __restrict__ ew,
                                                      float* deg, int* counts, int E) {
    int e = blockIdx.x * 256 + threadIdx.x;
    if (e < E) {
        int d = dst[e];
        atomicAdd(&deg[d], ew[e]);
        atomicAdd(&counts[d], 1);
    }
}

__global__ __launch_bounds__(256) void compute_dinv(float* deg, int N) {
    int i = blockIdx.x * 256 + threadIdx.x;
    if (i < N) deg[i] = rsqrtf(deg[i]);
}

#define SCAN_TILE 2048

__global__ __launch_bounds__(256) void scan1(const int* __restrict__ counts,
                                             int* __restrict__ rowptr,
                                             int* __restrict__ bsums, int N) {
    __shared__ int tmp[256];
    int t = threadIdx.x;
    int base = blockIdx.x * SCAN_TILE + t * 8;
    int v[8], s = 0;
#pragma unroll
    for (int j = 0; j < 8; ++j) { v[j] = (base + j < N) ? counts[base + j] : 0; s += v[j]; }
    tmp[t] = s;
    __syncthreads();
#pragma unroll
    for (int off = 1; off < 256; off <<= 1) {
        int u = (t >= off) ? tmp[t - off] : 0;
        __syncthreads();
        tmp[t] += u;
        __syncthreads();
    }
    int run = tmp[t] - s;
#pragma unroll
    for (int j = 0; j < 8; ++j) {
        if (base + j < N) rowptr[base + j] = run;
        run += v[j];
    }
    if (t == 255) bsums[blockIdx.x] = tmp[255];
}

__global__ __launch_bounds__(256) void scan2(int* bsums, int* rowptr, int NB, int N, int E) {
    __shared__ int tmp[256];
    int t = threadIdx.x;
    int v = (t < NB) ? bsums[t] : 0;
    tmp[t] = v;
    __syncthreads();
#pragma unroll
    for (int off = 1; off < 256; off <<= 1) {
        int u = (t >= off) ? tmp[t - off] : 0;
        __syncthreads();
        tmp[t] += u;
        __syncthreads();
    }
    if (t < NB) bsums[t] = tmp[t] - v;
    if (t == 0) rowptr[N] = E;
}

__global__ __launch_bounds__(256) void scan3(int* rowptr, const int* __restrict__ bsums, int N) {
    int base = blockIdx.x * SCAN_TILE + threadIdx.x * 8;
    int off = bsums[blockIdx.x];
#pragma unroll
    for (int j = 0; j < 8; ++j)
        if (base + j < N) rowptr[base + j] += off;
}

// (col,val) packed: one 8B scatter per edge instead of two 4B scatters
__global__ __launch_bounds__(256) void fill_csr(const int* __restrict__ src,
                                                const int* __restrict__ dst,
                                                const float* __restrict__ ew,
                                                const float* __restrict__ dinv,
                                                const int* __restrict__ rowptr,
                                                int* __restrict__ fillc,
                                                int2* __restrict__ cv, int E) {
    int e = blockIdx.x * 256 + threadIdx.x;
    if (e < E) {
        int d = dst[e], s = src[e];
        int pos = rowptr[d] + atomicAdd(&fillc[d], 1);
        float v = dinv[s] * ew[e] * dinv[d];
        cv[pos] = make_int2(s, __float_as_int(v));
    }
}

// --------- W[K][N] fp32 -> fp16 transposed [N][Kpad] (zero-padded K) -------
__global__ __launch_bounds__(256) void tohalf_w(const float* __restrict__ W,
                                                __half* __restrict__ WT,
                                                int K, int N, int Kpad) {
    int idx = blockIdx.x * 256 + threadIdx.x;
    int total = N * Kpad;
    if (idx >= total) return;
    int n = idx / Kpad, k = idx % Kpad;
    float v = (k < K) ? W[(size_t)k * N + n] : 0.0f;
    WT[idx] = __float2half(v);
}

// --------- x[N][K] fp32 -> fp16 [N][Kpad] ----------------------------------
__global__ __launch_bounds__(256) void tohalf_x(const float* __restrict__ x,
                                                __half* __restrict__ Xh,
                                                int Nn, int K, int Kpad) {
    int idx = blockIdx.x * 256 + threadIdx.x;  // one 8-elem chunk
    int cpr = Kpad / 8;
    int total = Nn * cpr;
    if (idx >= total) return;
    int row = idx / cpr, c = idx % cpr;
    int gk = c * 8;
    const float* p = x + (size_t)row * K + gk;
    float v[8];
    if (gk + 8 <= K) {
#pragma unroll
        for (int j = 0; j < 4; ++j) {
            float2 t2 = *(const float2*)(p + j * 2);  // 8B-aligned always
            v[j * 2] = t2.x; v[j * 2 + 1] = t2.y;
        }
    } else {
#pragma unroll
        for (int j = 0; j < 8; ++j) v[j] = (gk + j < K) ? p[j] : 0.0f;
    }
    union { __half2 h[4]; uint4 u; } pk;
#pragma unroll
    for (int j = 0; j < 4; ++j) pk.h[j] = __floats2half2_rn(v[j * 2], v[j * 2 + 1]);
    *(uint4*)&Xh[(size_t)row * Kpad + gk] = pk.u;
}

// ---------------- fp16 MFMA GEMM: C[M,BN](fp16) = A[M,Kpad] @ BT^T ---------
template <int BM, int BN, int WARPS_M, int WARPS_N, int NT>
__global__ __launch_bounds__(NT) void gemm_f16(const __half* __restrict__ Ah,
                                               const __half* __restrict__ BT,
                                               __half* __restrict__ C,
                                               int M, int Kpad) {
    const int WM = BM / WARPS_M, WN = BN / WARPS_N;
    const int FM = WM / 16, FN = WN / 16;
    const int ACH = BM * 4;              // 16B chunks for A tile
    const int BCH = BN * 4;              // for B tile
    const int TOTCH = ACH + BCH;
    const int CH = TOTCH / NT;
    static_assert(CH == 3, "vmcnt(3) hardcoded below");
    __shared__ __align__(16) __half lds[2][TOTCH * 8];

    int tid = threadIdx.x;
    int lane = tid & 63;
    int w = tid >> 6;
    int wr = w / WARPS_N, wc = w % WARPS_N;
    int bm = blockIdx.x * BM;
    int lrow = lane & 15;
    int lslot = lane >> 4;

    const __half* srcp[CH];
#pragma unroll
    for (int i = 0; i < CH; ++i) {
        int ch = tid + i * NT;
        if (ch < ACH) {
            int c = ch, row = c >> 2;
            int grow = bm + row;
            if (grow >= M) grow = M - 1;
            srcp[i] = Ah + (size_t)grow * Kpad + (size_t)(((c & 3) ^ ((row >> 1) & 3)) * 8);
        } else {
            int c = ch - ACH, row = c >> 2;
            srcp[i] = BT + (size_t)row * Kpad + (size_t)(((c & 3) ^ ((row >> 1) & 3)) * 8);
        }
    }

    f32x4 acc[FM][FN];
#pragma unroll
    for (int m = 0; m < FM; ++m)
#pragma unroll
        for (int n = 0; n < FN; ++n) acc[m][n] = (f32x4){0.f, 0.f, 0.f, 0.f};

    auto stage = [&](int buf) {
#pragma unroll
        for (int i = 0; i < CH; ++i) {
            async_copy16(srcp[i], &lds[buf][(size_t)((tid & ~63) + i * NT) * 8]);
            srcp[i] += 32;
        }
    };

    auto compute = [&](int buf) {
        f16x8 af[FM], bf[FN];
#pragma unroll
        for (int m = 0; m < FM; ++m) {
            int row = wr * WM + m * 16 + lrow;
            int p = lslot ^ ((row >> 1) & 3);
            af[m] = *(const f16x8*)&lds[buf][(size_t)(row * 4 + p) * 8];
        }
#pragma unroll
        for (int n = 0; n < FN; ++n) {
            int row = wc * WN + n * 16 + lrow;
            int p = lslot ^ ((row >> 1) & 3);
            bf[n] = *(const f16x8*)&lds[buf][(size_t)(ACH + row * 4 + p) * 8];
        }
#pragma unroll
        for (int m = 0; m < FM; ++m)
#pragma unroll
            for (int n = 0; n < FN; ++n)
                acc[m][n] = __builtin_amdgcn_mfma_f32_16x16x32_f16(af[m], bf[n], acc[m][n], 0, 0, 0);
    };

    const int nsteps = Kpad / 32;
    stage(0);
    for (int s = 0; s < nsteps; ++s) {
        if (s + 1 < nsteps) {
            stage((s + 1) & 1);
            asm volatile("s_waitcnt vmcnt(3)" ::: "memory");
        } else {
            asm volatile("s_waitcnt vmcnt(0)" ::: "memory");
        }
        __builtin_amdgcn_s_barrier();
        compute(s & 1);
        __builtin_amdgcn_s_barrier();
    }

#pragma unroll
    for (int m = 0; m < FM; ++m) {
        int rb = bm + wr * WM + m * 16 + (lane >> 4) * 4;
#pragma unroll
        for (int n = 0; n < FN; ++n) {
            int cb = wc * WN + n * 16 + (lane & 15);
#pragma unroll
            for (int i = 0; i < 4; ++i) {
                int r = rb + i;
                if (r < M) C[(size_t)r * BN + cb] = __float2half(acc[m][n][i]);
            }
        }
    }
}

// ---- gather aggregation (fp16 features, fp32 accum, 8x unrolled) ----------
// out[d] = bias + dinv[d]^2*xw[d] + sum_p val[p]*xw[col[p]]  (; relu)
template <int F, int LPN, int RELU, typename OutT>
__global__ __launch_bounds__(256) void gatherh(const int* __restrict__ rowptr,
                                               const int2* __restrict__ cv,
                                               const __half* __restrict__ xw,
                                               const float* __restrict__ dinv,
                                               const float* __restrict__ bias,
                                               OutT* __restrict__ out, int N) {
    const int NPB = 256 / LPN;
    int d = blockIdx.x * NPB + threadIdx.x / LPN;
    if (d >= N) return;
    int lane = threadIdx.x % LPN;

    float di = dinv[d];
    float w = di * di;
    uint2 raw = *(const uint2*)(xw + (size_t)d * F + lane * 4);
    float2 u0 = __half22float2(*(__half2*)&raw.x);
    float2 u1 = __half22float2(*(__half2*)&raw.y);
    float a0 = w * u0.x, a1 = w * u0.y, a2 = w * u1.x, a3 = w * u1.y;
    float b0 = 0.f, b1 = 0.f, b2 = 0.f, b3 = 0.f;  // second accum set

    int p = rowptr[d], p1 = rowptr[d + 1];
    for (; p + 8 <= p1; p += 8) {
        int2 e[8];
        uint2 r[8];
#pragma unroll
        for (int j = 0; j < 8; ++j) e[j] = cv[p + j];
#pragma unroll
        for (int j = 0; j < 8; ++j)
            r[j] = *(const uint2*)(xw + (size_t)e[j].x * F + lane * 4);
#pragma unroll
        for (int j = 0; j < 8; ++j) {
            float wv = __int_as_float(e[j].y);
            float2 v0 = __half22float2(*(__half2*)&r[j].x);
            float2 v1 = __half22float2(*(__half2*)&r[j].y);
            if (j & 1) {
                b0 = fmaf(wv, v0.x, b0); b1 = fmaf(wv, v0.y, b1);
                b2 = fmaf(wv, v1.x, b2); b3 = fmaf(wv, v1.y, b3);
            } else {
                a0 = fmaf(wv, v0.x, a0); a1 = fmaf(wv, v0.y, a1);
                a2 = fmaf(wv, v1.x, a2); a3 = fmaf(wv, v1.y, a3);
            }
        }
    }
    for (; p < p1; ++p) {
        int2 e = cv[p];
        float wv = __int_as_float(e.y);
        uint2 rv = *(const uint2*)(xw + (size_t)e.x * F + lane * 4);
        float2 v0 = __half22float2(*(__half2*)&rv.x);
        float2 v1 = __half22float2(*(__half2*)&rv.y);
        a0 = fmaf(wv, v0.x, a0); a1 = fmaf(wv, v0.y, a1);
        a2 = fmaf(wv, v1.x, a2); a3 = fmaf(wv, v1.y, a3);
    }
    a0 += b0; a1 += b1; a2 += b2; a3 += b3;

    float4 bb = *(const float4*)&bias[lane * 4];
    a0 += bb.x; a1 += bb.y; a2 += bb.z; a3 += bb.w;
    if (RELU) {
        a0 = fmaxf(a0, 0.f); a1 = fmaxf(a1, 0.f);
        a2 = fmaxf(a2, 0.f); a3 = fmaxf(a3, 0.f);
    }
    if constexpr (std::is_same_v<OutT, float>) {
        *(float4*)&out[(size_t)d * F + lane * 4] = make_float4(a0, a1, a2, a3);
    } else {
        __half2 h0 = __floats2half2_rn(a0, a1);
        __half2 h1 = __floats2half2_rn(a2, a3);
        uint2 packed;
        packed.x = *(uint*)&h0;
        packed.y = *(uint*)&h1;
        *(uint2*)&out[(size_t)d * F + lane * 4] = packed;
    }
}

extern "C" void kernel_launch(void* const* d_in, const int* in_sizes, int n_in,
                              void* d_out, int out_size, void* d_ws, size_t ws_size,
                              hipStream_t stream) {
    const float* x  = (const float*)d_in[0];
    const int*   ei = (const int*)d_in[1];
    const float* ew = (const float*)d_in[2];
    const float* W1 = (const float*)d_in[3];
    const float* b1 = (const float*)d_in[4];
    const float* W2 = (const float*)d_in[5];
    const float* b2 = (const float*)d_in[6];
    float* out = (float*)d_out;

    const int H    = in_sizes[4];            // 256
    const int Fout = in_sizes[6];            // 64
    const int Fin  = in_sizes[3] / H;        // 394
    const int N    = in_sizes[0] / Fin;      // 100000
    const int E    = in_sizes[2];            // 1600000

    const int Kpad1 = (Fin + 31) / 32 * 32;  // 416
    const int Kpad2 = (H + 31) / 32 * 32;    // 256

    const int* src = ei;
    const int* dst = ei + E;

    // workspace layout (all sections 16B aligned)
    float* ws     = (float*)d_ws;
    float* dinv   = ws;                           // N
    int*   counts = (int*)(dinv + N);             // N
    int*   fillc  = counts + N;                   // N
    int*   rowptr = fillc + N;                    // N+4
    int*   bsums  = rowptr + N + 4;               // 256
    int2*  cv     = (int2*)(bsums + 256);         // E int2 (col,val)
    __half* bufA  = (__half*)(cv + E);            // N*H (xw1, later xw2)
    __half* bufB  = bufA + (size_t)N * H;         // N*H (h)
    __half* xh    = bufB + (size_t)N * H;         // N*Kpad1
    __half* wt1   = xh + (size_t)N * Kpad1;       // H*Kpad1
    __half* wt2   = wt1 + (size_t)H * Kpad1;      // Fout*Kpad2

    const int NB = (N + SCAN_TILE - 1) / SCAN_TILE;

    // 1. degrees + histogram + dinv
    init_node<<<(N + 255) / 256, 256, 0, stream>>>(dinv, counts, fillc, N);
    accum_deg_hist<<<(E + 255) / 256, 256, 0, stream>>>(dst, ew, dinv, counts, E);
    compute_dinv<<<(N + 255) / 256, 256, 0, stream>>>(dinv, N);

    // 2. CSR build
    scan1<<<NB, 256, 0, stream>>>(counts, rowptr, bsums, N);
    scan2<<<1, 256, 0, stream>>>(bsums, rowptr, NB, N, E);
    scan3<<<NB, 256, 0, stream>>>(rowptr, bsums, N);
    fill_csr<<<(E + 255) / 256, 256, 0, stream>>>(src, dst, ew, dinv, rowptr, fillc, cv, E);

    // 3. fp16 conversions
    tohalf_w<<<(H * Kpad1 + 255) / 256, 256, 0, stream>>>(W1, wt1, Fin, H, Kpad1);
    tohalf_w<<<(Fout * Kpad2 + 255) / 256, 256, 0, stream>>>(W2, wt2, H, Fout, Kpad2);
    tohalf_x<<<((size_t)N * (Kpad1 / 8) + 255) / 256, 256, 0, stream>>>(x, xh, N, Fin, Kpad1);

    // 4. xw1 = x @ W1   [N,394]@[394,256] -> fp16
    gemm_f16<128, 256, 2, 4, 512><<<(N + 127) / 128, 512, 0, stream>>>(xh, wt1, bufA, N, Kpad1);

    // 5. h = relu(gather + bias) -> fp16
    gatherh<256, 64, 1, __half><<<(N + 3) / 4, 256, 0, stream>>>(
        rowptr, cv, bufA, dinv, b1, bufB, N);

    // 6. xw2 = h @ W2   [N,256]@[256,64] -> fp16
    gemm_f16<128, 64, 2, 2, 256><<<(N + 127) / 128, 256, 0, stream>>>(bufB, wt2, bufA, N, Kpad2);

    // 7. out = gather + bias -> fp32
    gatherh<64, 16, 0, float><<<(N + 15) / 16, 256, 0, stream>>>(
        rowptr, cv, bufA, dinv, b2, out, N);
}

// Round 11
// 553.509 us; speedup vs baseline: 1.0055x; 1.0055x over previous
//
#include <hip/hip_runtime.h>
#include <hip/hip_bf16.h>
#include <hip/hip_fp16.h>
#include <type_traits>

// ---------------------------------------------------------------------------
// 2-layer GCN. CSR-gather aggregation (fp16 features, fp32 accum, 4x-unrolled
// edge loop for MLP — 8x was a measured regression). (col,val) packed int2.
// Preprocessing: (deg,count) packed in one cache line per node; cursor-based
// CSR fill (single atomic per edge, no random rowptr read).
// GEMMs: fp16 MFMA (fp32 accumulate), global_load_lds double-buffered staging
// with counted vmcnt(3) + raw s_barrier.
// ---------------------------------------------------------------------------

typedef _Float16 f16x8 __attribute__((ext_vector_type(8)));
typedef float f32x4 __attribute__((ext_vector_type(4)));

__device__ inline void async_copy16(const void* g, void* l) {
    __builtin_amdgcn_global_load_lds(
        (const __attribute__((address_space(1))) void*)g,
        (__attribute__((address_space(3))) void*)l, 16, 0, 0);
}

// ------------------------- graph preprocessing -----------------------------
// packed[2i] = deg (float, init 1.0 for self-loop); packed[2i+1] = count (int)

__global__ __launch_bounds__(256) void init_node(float* packed, int N) {
    int i = blockIdx.x * 256 + threadIdx.x;
    if (i < N) {
        packed[2 * i] = 1.0f;
        ((int*)packed)[2 * i + 1] = 0;
    }
}

__global__ __launch_bounds__(256) void accum_deg_hist(const int* __restrict__ dst,
                                                      const float* __restrict__ ew,
                                                      float* packed, int E) {
    int e = blockIdx.x * 256 + threadIdx.x;
    if (e < E) {
        int d = dst[e];
        atomicAdd(&packed[2 * d], ew[e]);        // same 64B line as the count
        atomicAdd(&((int*)packed)[2 * d + 1], 1);
    }
}

__global__ __launch_bounds__(256) void compute_dinv(const float* __restrict__ packed,
                                                    float* __restrict__ dinv, int N) {
    int i = blockIdx.x * 256 + threadIdx.x;
    if (i < N) dinv[i] = rsqrtf(packed[2 * i]);
}

#define SCAN_TILE 2048

__global__ __launch_bounds__(256) void scan1(const float* __restrict__ packed,
                                             int* __restrict__ rowptr,
                                             int* __restrict__ bsums, int N) {
    __shared__ int tmp[256];
    int t = threadIdx.x;
    int base = blockIdx.x * SCAN_TILE + t * 8;
    const int* pc = (const int*)packed;
    int v[8], s = 0;
#pragma unroll
    for (int j = 0; j < 8; ++j) { v[j] = (base + j < N) ? pc[2 * (base + j) + 1] : 0; s += v[j]; }
    tmp[t] = s;
    __syncthreads();
#pragma unroll
    for (int off = 1; off < 256; off <<= 1) {
        int u = (t >= off) ? tmp[t - off] : 0;
        __syncthreads();
        tmp[t] += u;
        __syncthreads();
    }
    int run = tmp[t] - s;
#pragma unroll
    for (int j = 0; j < 8; ++j) {
        if (base + j < N) rowptr[base + j] = run;
        run += v[j];
    }
    if (t == 255) bsums[blockIdx.x] = tmp[255];
}

__global__ __launch_bounds__(256) void scan2(int* bsums, int* rowptr, int NB, int N, int E) {
    __shared__ int tmp[256];
    int t = threadIdx.x;
    int v = (t < NB) ? bsums[t] : 0;
    tmp[t] = v;
    __syncthreads();
#pragma unroll
    for (int off = 1; off < 256; off <<= 1) {
        int u = (t >= off) ? tmp[t - off] : 0;
        __syncthreads();
        tmp[t] += u;
        __syncthreads();
    }
    if (t < NB) bsums[t] = tmp[t] - v;
    if (t == 0) rowptr[N] = E;
}

// writes final rowptr AND initializes cursor = rowptr (for cursor-based fill)
__global__ __launch_bounds__(256) void scan3(int* rowptr, int* cursor,
                                             const int* __restrict__ bsums, int N) {
    int base = blockIdx.x * SCAN_TILE + threadIdx.x * 8;
    int off = bsums[blockIdx.x];
#pragma unroll
    for (int j = 0; j < 8; ++j)
        if (base + j < N) {
            int v = rowptr[base + j] + off;
            rowptr[base + j] = v;
            cursor[base + j] = v;
        }
}

// single atomic per edge; (col,val) packed as one 8B store
__global__ __launch_bounds__(256) void fill_csr(const int* __restrict__ src,
                                                const int* __restrict__ dst,
                                                const float* __restrict__ ew,
                                                const float* __restrict__ dinv,
                                                int* __restrict__ cursor,
                                                int2* __restrict__ cv, int E) {
    int e = blockIdx.x * 256 + threadIdx.x;
    if (e < E) {
        int d = dst[e], s = src[e];
        int pos = atomicAdd(&cursor[d], 1);
        float v = dinv[s] * ew[e] * dinv[d];
        cv[pos] = make_int2(s, __float_as_int(v));
    }
}

// --------- W[K][N] fp32 -> fp16 transposed [N][Kpad] (zero-padded K) -------
__global__ __launch_bounds__(256) void tohalf_w(const float* __restrict__ W,
                                                __half* __restrict__ WT,
                                                int K, int N, int Kpad) {
    int idx = blockIdx.x * 256 + threadIdx.x;
    int total = N * Kpad;
    if (idx >= total) return;
    int n = idx / Kpad, k = idx % Kpad;
    float v = (k < K) ? W[(size_t)k * N + n] : 0.0f;
    WT[idx] = __float2half(v);
}

// --------- x[N][K] fp32 -> fp16 [N][Kpad] ----------------------------------
__global__ __launch_bounds__(256) void tohalf_x(const float* __restrict__ x,
                                                __half* __restrict__ Xh,
                                                int Nn, int K, int Kpad) {
    int idx = blockIdx.x * 256 + threadIdx.x;  // one 8-elem chunk
    int cpr = Kpad / 8;
    int total = Nn * cpr;
    if (idx >= total) return;
    int row = idx / cpr, c = idx % cpr;
    int gk = c * 8;
    const float* p = x + (size_t)row * K + gk;
    float v[8];
    if (gk + 8 <= K) {
#pragma unroll
        for (int j = 0; j < 4; ++j) {
            float2 t2 = *(const float2*)(p + j * 2);  // 8B-aligned always
            v[j * 2] = t2.x; v[j * 2 + 1] = t2.y;
        }
    } else {
#pragma unroll
        for (int j = 0; j < 8; ++j) v[j] = (gk + j < K) ? p[j] : 0.0f;
    }
    union { __half2 h[4]; uint4 u; } pk;
#pragma unroll
    for (int j = 0; j < 4; ++j) pk.h[j] = __floats2half2_rn(v[j * 2], v[j * 2 + 1]);
    *(uint4*)&Xh[(size_t)row * Kpad + gk] = pk.u;
}

// ---------------- fp16 MFMA GEMM: C[M,BN](fp16) = A[M,Kpad] @ BT^T ---------
template <int BM, int BN, int WARPS_M, int WARPS_N, int NT>
__global__ __launch_bounds__(NT) void gemm_f16(const __half* __restrict__ Ah,
                                               const __half* __restrict__ BT,
                                               __half* __restrict__ C,
                                               int M, int Kpad) {
    const int WM = BM / WARPS_M, WN = BN / WARPS_N;
    const int FM = WM / 16, FN = WN / 16;
    const int ACH = BM * 4;              // 16B chunks for A tile
    const int BCH = BN * 4;              // for B tile
    const int TOTCH = ACH + BCH;
    const int CH = TOTCH / NT;
    static_assert(CH == 3, "vmcnt(3) hardcoded below");
    __shared__ __align__(16) __half lds[2][TOTCH * 8];

    int tid = threadIdx.x;
    int lane = tid & 63;
    int w = tid >> 6;
    int wr = w / WARPS_N, wc = w % WARPS_N;
    int bm = blockIdx.x * BM;
    int lrow = lane & 15;
    int lslot = lane >> 4;

    const __half* srcp[CH];
#pragma unroll
    for (int i = 0; i < CH; ++i) {
        int ch = tid + i * NT;
        if (ch < ACH) {
            int c = ch, row = c >> 2;
            int grow = bm + row;
            if (grow >= M) grow = M - 1;
            srcp[i] = Ah + (size_t)grow * Kpad + (size_t)(((c & 3) ^ ((row >> 1) & 3)) * 8);
        } else {
            int c = ch - ACH, row = c >> 2;
            srcp[i] = BT + (size_t)row * Kpad + (size_t)(((c & 3) ^ ((row >> 1) & 3)) * 8);
        }
    }

    f32x4 acc[FM][FN];
#pragma unroll
    for (int m = 0; m < FM; ++m)
#pragma unroll
        for (int n = 0; n < FN; ++n) acc[m][n] = (f32x4){0.f, 0.f, 0.f, 0.f};

    auto stage = [&](int buf) {
#pragma unroll
        for (int i = 0; i < CH; ++i) {
            async_copy16(srcp[i], &lds[buf][(size_t)((tid & ~63) + i * NT) * 8]);
            srcp[i] += 32;
        }
    };

    auto compute = [&](int buf) {
        f16x8 af[FM], bf[FN];
#pragma unroll
        for (int m = 0; m < FM; ++m) {
            int row = wr * WM + m * 16 + lrow;
            int p = lslot ^ ((row >> 1) & 3);
            af[m] = *(const f16x8*)&lds[buf][(size_t)(row * 4 + p) * 8];
        }
#pragma unroll
        for (int n = 0; n < FN; ++n) {
            int row = wc * WN + n * 16 + lrow;
            int p = lslot ^ ((row >> 1) & 3);
            bf[n] = *(const f16x8*)&lds[buf][(size_t)(ACH + row * 4 + p) * 8];
        }
#pragma unroll
        for (int m = 0; m < FM; ++m)
#pragma unroll
            for (int n = 0; n < FN; ++n)
                acc[m][n] = __builtin_amdgcn_mfma_f32_16x16x32_f16(af[m], bf[n], acc[m][n], 0, 0, 0);
    };

    const int nsteps = Kpad / 32;
    stage(0);
    for (int s = 0; s < nsteps; ++s) {
        if (s + 1 < nsteps) {
            stage((s + 1) & 1);
            asm volatile("s_waitcnt vmcnt(3)" ::: "memory");
        } else {
            asm volatile("s_waitcnt vmcnt(0)" ::: "memory");
        }
        __builtin_amdgcn_s_barrier();
        compute(s & 1);
        __builtin_amdgcn_s_barrier();
    }

#pragma unroll
    for (int m = 0; m < FM; ++m) {
        int rb = bm + wr * WM + m * 16 + (lane >> 4) * 4;
#pragma unroll
        for (int n = 0; n < FN; ++n) {
            int cb = wc * WN + n * 16 + (lane & 15);
#pragma unroll
            for (int i = 0; i < 4; ++i) {
                int r = rb + i;
                if (r < M) C[(size_t)r * BN + cb] = __float2half(acc[m][n][i]);
            }
        }
    }
}

// ---- gather aggregation (fp16 features, fp32 accum, 4x unrolled) ----------
// out[d] = bias + dinv[d]^2*xw[d] + sum_p val[p]*xw[col[p]]  (; relu)
template <int F, int LPN, int RELU, typename OutT>
__global__ __launch_bounds__(256) void gatherh(const int* __restrict__ rowptr,
                                               const int2* __restrict__ cv,
                                               const __half* __restrict__ xw,
                                               const float* __restrict__ dinv,
                                               const float* __restrict__ bias,
                                               OutT* __restrict__ out, int N) {
    const int NPB = 256 / LPN;
    int d = blockIdx.x * NPB + threadIdx.x / LPN;
    if (d >= N) return;
    int lane = threadIdx.x % LPN;

    float di = dinv[d];
    float w = di * di;
    uint2 raw = *(const uint2*)(xw + (size_t)d * F + lane * 4);
    float2 u0 = __half22float2(*(__half2*)&raw.x);
    float2 u1 = __half22float2(*(__half2*)&raw.y);
    float a0 = w * u0.x, a1 = w * u0.y, a2 = w * u1.x, a3 = w * u1.y;
    float b0 = 0.f, b1 = 0.f, b2 = 0.f, b3 = 0.f;  // second accum set

    int p = rowptr[d], p1 = rowptr[d + 1];
    for (; p + 4 <= p1; p += 4) {
        int2 e0 = cv[p], e1 = cv[p + 1], e2 = cv[p + 2], e3 = cv[p + 3];
        uint2 r0 = *(const uint2*)(xw + (size_t)e0.x * F + lane * 4);
        uint2 r1 = *(const uint2*)(xw + (size_t)e1.x * F + lane * 4);
        uint2 r2 = *(const uint2*)(xw + (size_t)e2.x * F + lane * 4);
        uint2 r3 = *(const uint2*)(xw + (size_t)e3.x * F + lane * 4);
        float w0 = __int_as_float(e0.y), w1 = __int_as_float(e1.y);
        float w2 = __int_as_float(e2.y), w3 = __int_as_float(e3.y);
        {
            float2 v0 = __half22float2(*(__half2*)&r0.x);
            float2 v1 = __half22float2(*(__half2*)&r0.y);
            a0 = fmaf(w0, v0.x, a0); a1 = fmaf(w0, v0.y, a1);
            a2 = fmaf(w0, v1.x, a2); a3 = fmaf(w0, v1.y, a3);
        }
        {
            float2 v0 = __half22float2(*(__half2*)&r1.x);
            float2 v1 = __half22float2(*(__half2*)&r1.y);
            b0 = fmaf(w1, v0.x, b0); b1 = fmaf(w1, v0.y, b1);
            b2 = fmaf(w1, v1.x, b2); b3 = fmaf(w1, v1.y, b3);
        }
        {
            float2 v0 = __half22float2(*(__half2*)&r2.x);
            float2 v1 = __half22float2(*(__half2*)&r2.y);
            a0 = fmaf(w2, v0.x, a0); a1 = fmaf(w2, v0.y, a1);
            a2 = fmaf(w2, v1.x, a2); a3 = fmaf(w2, v1.y, a3);
        }
        {
            float2 v0 = __half22float2(*(__half2*)&r3.x);
            float2 v1 = __half22float2(*(__half2*)&r3.y);
            b0 = fmaf(w3, v0.x, b0); b1 = fmaf(w3, v0.y, b1);
            b2 = fmaf(w3, v1.x, b2); b3 = fmaf(w3, v1.y, b3);
        }
    }
    for (; p < p1; ++p) {
        int2 e = cv[p];
        float wv = __int_as_float(e.y);
        uint2 rv = *(const uint2*)(xw + (size_t)e.x * F + lane * 4);
        float2 v0 = __half22float2(*(__half2*)&rv.x);
        float2 v1 = __half22float2(*(__half2*)&rv.y);
        a0 = fmaf(wv, v0.x, a0); a1 = fmaf(wv, v0.y, a1);
        a2 = fmaf(wv, v1.x, a2); a3 = fmaf(wv, v1.y, a3);
    }
    a0 += b0; a1 += b1; a2 += b2; a3 += b3;

    float4 bb = *(const float4*)&bias[lane * 4];
    a0 += bb.x; a1 += bb.y; a2 += bb.z; a3 += bb.w;
    if (RELU) {
        a0 = fmaxf(a0, 0.f); a1 = fmaxf(a1, 0.f);
        a2 = fmaxf(a2, 0.f); a3 = fmaxf(a3, 0.f);
    }
    if constexpr (std::is_same_v<OutT, float>) {
        *(float4*)&out[(size_t)d * F + lane * 4] = make_float4(a0, a1, a2, a3);
    } else {
        __half2 h0 = __floats2half2_rn(a0, a1);
        __half2 h1 = __floats2half2_rn(a2, a3);
        uint2 packed;
        packed.x = *(uint*)&h0;
        packed.y = *(uint*)&h1;
        *(uint2*)&out[(size_t)d * F + lane * 4] = packed;
    }
}

extern "C" void kernel_launch(void* const* d_in, const int* in_sizes, int n_in,
                              void* d_out, int out_size, void* d_ws, size_t ws_size,
                              hipStream_t stream) {
    const float* x  = (const float*)d_in[0];
    const int*   ei = (const int*)d_in[1];
    const float* ew = (const float*)d_in[2];
    const float* W1 = (const float*)d_in[3];
    const float* b1 = (const float*)d_in[4];
    const float* W2 = (const float*)d_in[5];
    const float* b2 = (const float*)d_in[6];
    float* out = (float*)d_out;

    const int H    = in_sizes[4];            // 256
    const int Fout = in_sizes[6];            // 64
    const int Fin  = in_sizes[3] / H;        // 394
    const int N    = in_sizes[0] / Fin;      // 100000
    const int E    = in_sizes[2];            // 1600000

    const int Kpad1 = (Fin + 31) / 32 * 32;  // 416
    const int Kpad2 = (H + 31) / 32 * 32;    // 256

    const int* src = ei;
    const int* dst = ei + E;

    // workspace layout (all sections 16B aligned)
    float* ws     = (float*)d_ws;
    float* packed = ws;                           // 2N (deg,count interleaved)
    float* dinv   = packed + 2 * (size_t)N;       // N
    int*   rowptr = (int*)(dinv + N);             // N+4
    int*   cursor = rowptr + N + 4;               // N+4
    int*   bsums  = cursor + N + 4;               // 256
    int2*  cv     = (int2*)(bsums + 256);         // E int2 (col,val)
    __half* bufA  = (__half*)(cv + E);            // N*H (xw1, later xw2)
    __half* bufB  = bufA + (size_t)N * H;         // N*H (h)
    __half* xh    = bufB + (size_t)N * H;         // N*Kpad1
    __half* wt1   = xh + (size_t)N * Kpad1;       // H*Kpad1
    __half* wt2   = wt1 + (size_t)H * Kpad1;      // Fout*Kpad2

    const int NB = (N + SCAN_TILE - 1) / SCAN_TILE;

    // 1. degrees + histogram (one cache line per node) + dinv
    init_node<<<(N + 255) / 256, 256, 0, stream>>>(packed, N);
    accum_deg_hist<<<(E + 255) / 256, 256, 0, stream>>>(dst, ew, packed, E);
    compute_dinv<<<(N + 255) / 256, 256, 0, stream>>>(packed, dinv, N);

    // 2. CSR build (cursor-based fill: one atomic per edge)
    scan1<<<NB, 256, 0, stream>>>(packed, rowptr, bsums, N);
    scan2<<<1, 256, 0, stream>>>(bsums, rowptr, NB, N, E);
    scan3<<<NB, 256, 0, stream>>>(rowptr, cursor, bsums, N);
    fill_csr<<<(E + 255) / 256, 256, 0, stream>>>(src, dst, ew, dinv, cursor, cv, E);

    // 3. fp16 conversions
    tohalf_w<<<(H * Kpad1 + 255) / 256, 256, 0, stream>>>(W1, wt1, Fin, H, Kpad1);
    tohalf_w<<<(Fout * Kpad2 + 255) / 256, 256, 0, stream>>>(W2, wt2, H, Fout, Kpad2);
    tohalf_x<<<((size_t)N * (Kpad1 / 8) + 255) / 256, 256, 0, stream>>>(x, xh, N, Fin, Kpad1);

    // 4. xw1 = x @ W1   [N,394]@[394,256] -> fp16
    gemm_f16<128, 256, 2, 4, 512><<<(N + 127) / 128, 512, 0, stream>>>(xh, wt1, bufA, N, Kpad1);

    // 5. h = relu(gather + bias) -> fp16
    gatherh<256, 64, 1, __half><<<(N + 3) / 4, 256, 0, stream>>>(
        rowptr, cv, bufA, dinv, b1, bufB, N);

    // 6. xw2 = h @ W2   [N,256]@[256,64] -> fp16
    gemm_f16<128, 64, 2, 2, 256><<<(N + 127) / 128, 256, 0, stream>>>(bufB, wt2, bufA, N, Kpad2);

    // 7. out = gather + bias -> fp32
    gatherh<64, 16, 0, float><<<(N + 15) / 16, 256, 0, stream>>>(
        rowptr, cv, bufA, dinv, b2, out, N);
}

// Round 12
// 476.252 us; speedup vs baseline: 1.1686x; 1.1622x over previous
//
#include <hip/hip_runtime.h>
#include <hip/hip_bf16.h>
#include <hip/hip_fp16.h>
#include <type_traits>

// ---------------------------------------------------------------------------
// 2-layer GCN. CSR-gather aggregation (fp16 features, fp32 accum, 4x-unrolled
// edge loop). (col,val) packed int2. Preprocessing: ONE 64-bit packed atomic
// per edge (count<<42 | fixed-point weighted deg); dinv fused into scan1;
// cursor-based CSR fill. GEMMs: fp16 MFMA, global_load_lds double-buffered
// staging, counted vmcnt(3) + raw s_barrier, LDS-bounce vectorized epilogue.
// ---------------------------------------------------------------------------

typedef _Float16 f16x8 __attribute__((ext_vector_type(8)));
typedef float f32x4 __attribute__((ext_vector_type(4)));

#define DEG_MASK ((1ull << 42) - 1)

__device__ inline void async_copy16(const void* g, void* l) {
    __builtin_amdgcn_global_load_lds(
        (const __attribute__((address_space(1))) void*)g,
        (__attribute__((address_space(3))) void*)l, 16, 0, 0);
}

// ------------------------- graph preprocessing -----------------------------
// packed[i]: bits [63:42] = edge count, bits [41:0] = sum(ew) in 2^-32 fixed pt

__global__ __launch_bounds__(256) void init_node(unsigned long long* packed, int N) {
    int i = blockIdx.x * 256 + threadIdx.x;
    if (i < N) packed[i] = 0ull;
}

__global__ __launch_bounds__(256) void accum_deg_hist(const int* __restrict__ dst,
                                                      const float* __restrict__ ew,
                                                      unsigned long long* packed, int E) {
    int e = blockIdx.x * 256 + threadIdx.x;
    if (e < E) {
        int d = dst[e];
        unsigned long long add =
            (1ull << 42) + (unsigned long long)(ew[e] * 4294967296.0f);
        atomicAdd(&packed[d], add);
    }
}

#define SCAN_TILE 2048

// exclusive scan of counts; also computes dinv = rsqrt(1 + deg) per node
__global__ __launch_bounds__(256) void scan1(const unsigned long long* __restrict__ packed,
                                             int* __restrict__ rowptr,
                                             float* __restrict__ dinv,
                                             int* __restrict__ bsums, int N) {
    __shared__ int tmp[256];
    int t = threadIdx.x;
    int base = blockIdx.x * SCAN_TILE + t * 8;
    int v[8], s = 0;
#pragma unroll
    for (int j = 0; j < 8; ++j) {
        int idx = base + j;
        if (idx < N) {
            unsigned long long pv = packed[idx];
            v[j] = (int)(pv >> 42);
            dinv[idx] = rsqrtf(1.0f + (float)(pv & DEG_MASK) * (1.0f / 4294967296.0f));
        } else v[j] = 0;
        s += v[j];
    }
    tmp[t] = s;
    __syncthreads();
#pragma unroll
    for (int off = 1; off < 256; off <<= 1) {
        int u = (t >= off) ? tmp[t - off] : 0;
        __syncthreads();
        tmp[t] += u;
        __syncthreads();
    }
    int run = tmp[t] - s;
#pragma unroll
    for (int j = 0; j < 8; ++j) {
        if (base + j < N) rowptr[base + j] = run;
        run += v[j];
    }
    if (t == 255) bsums[blockIdx.x] = tmp[255];
}

__global__ __launch_bounds__(256) void scan2(int* bsums, int* rowptr, int NB, int N, int E) {
    __shared__ int tmp[256];
    int t = threadIdx.x;
    int v = (t < NB) ? bsums[t] : 0;
    tmp[t] = v;
    __syncthreads();
#pragma unroll
    for (int off = 1; off < 256; off <<= 1) {
        int u = (t >= off) ? tmp[t - off] : 0;
        __syncthreads();
        tmp[t] += u;
        __syncthreads();
    }
    if (t < NB) bsums[t] = tmp[t] - v;
    if (t == 0) rowptr[N] = E;
}

// writes final rowptr AND initializes cursor = rowptr
__global__ __launch_bounds__(256) void scan3(int* rowptr, int* cursor,
                                             const int* __restrict__ bsums, int N) {
    int base = blockIdx.x * SCAN_TILE + threadIdx.x * 8;
    int off = bsums[blockIdx.x];
#pragma unroll
    for (int j = 0; j < 8; ++j)
        if (base + j < N) {
            int v = rowptr[base + j] + off;
            rowptr[base + j] = v;
            cursor[base + j] = v;
        }
}

// single atomic per edge; (col,val) packed as one 8B store
__global__ __launch_bounds__(256) void fill_csr(const int* __restrict__ src,
                                                const int* __restrict__ dst,
                                                const float* __restrict__ ew,
                                                const float* __restrict__ dinv,
                                                int* __restrict__ cursor,
                                                int2* __restrict__ cv, int E) {
    int e = blockIdx.x * 256 + threadIdx.x;
    if (e < E) {
        int d = dst[e], s = src[e];
        int pos = atomicAdd(&cursor[d], 1);
        float v = dinv[s] * ew[e] * dinv[d];
        cv[pos] = make_int2(s, __float_as_int(v));
    }
}

// --------- W[K][N] fp32 -> fp16 transposed [N][Kpad] (zero-padded K) -------
__global__ __launch_bounds__(256) void tohalf_w(const float* __restrict__ W,
                                                __half* __restrict__ WT,
                                                int K, int N, int Kpad) {
    int idx = blockIdx.x * 256 + threadIdx.x;
    int total = N * Kpad;
    if (idx >= total) return;
    int n = idx / Kpad, k = idx % Kpad;
    float v = (k < K) ? W[(size_t)k * N + n] : 0.0f;
    WT[idx] = __float2half(v);
}

// --------- x[N][K] fp32 -> fp16 [N][Kpad] ----------------------------------
__global__ __launch_bounds__(256) void tohalf_x(const float* __restrict__ x,
                                                __half* __restrict__ Xh,
                                                int Nn, int K, int Kpad) {
    int idx = blockIdx.x * 256 + threadIdx.x;  // one 8-elem chunk
    int cpr = Kpad / 8;
    int total = Nn * cpr;
    if (idx >= total) return;
    int row = idx / cpr, c = idx % cpr;
    int gk = c * 8;
    const float* p = x + (size_t)row * K + gk;
    float v[8];
    if (gk + 8 <= K) {
#pragma unroll
        for (int j = 0; j < 4; ++j) {
            float2 t2 = *(const float2*)(p + j * 2);  // 8B-aligned always
            v[j * 2] = t2.x; v[j * 2 + 1] = t2.y;
        }
    } else {
#pragma unroll
        for (int j = 0; j < 8; ++j) v[j] = (gk + j < K) ? p[j] : 0.0f;
    }
    union { __half2 h[4]; uint4 u; } pk;
#pragma unroll
    for (int j = 0; j < 4; ++j) pk.h[j] = __floats2half2_rn(v[j * 2], v[j * 2 + 1]);
    *(uint4*)&Xh[(size_t)row * Kpad + gk] = pk.u;
}

// ---------------- fp16 MFMA GEMM: C[M,BN](fp16) = A[M,Kpad] @ BT^T ---------
template <int BM, int BN, int WARPS_M, int WARPS_N, int NT>
__global__ __launch_bounds__(NT) void gemm_f16(const __half* __restrict__ Ah,
                                               const __half* __restrict__ BT,
                                               __half* __restrict__ C,
                                               int M, int Kpad) {
    const int WM = BM / WARPS_M, WN = BN / WARPS_N;
    const int FM = WM / 16, FN = WN / 16;
    const int ACH = BM * 4;              // 16B chunks for A tile
    const int BCH = BN * 4;              // for B tile
    const int TOTCH = ACH + BCH;
    const int CH = TOTCH / NT;
    static_assert(CH == 3, "vmcnt(3) hardcoded below");
    __shared__ __align__(16) __half lds[2][TOTCH * 8];

    int tid = threadIdx.x;
    int lane = tid & 63;
    int w = tid >> 6;
    int wr = w / WARPS_N, wc = w % WARPS_N;
    int bm = blockIdx.x * BM;
    int lrow = lane & 15;
    int lslot = lane >> 4;

    const __half* srcp[CH];
#pragma unroll
    for (int i = 0; i < CH; ++i) {
        int ch = tid + i * NT;
        if (ch < ACH) {
            int c = ch, row = c >> 2;
            int grow = bm + row;
            if (grow >= M) grow = M - 1;
            srcp[i] = Ah + (size_t)grow * Kpad + (size_t)(((c & 3) ^ ((row >> 1) & 3)) * 8);
        } else {
            int c = ch - ACH, row = c >> 2;
            srcp[i] = BT + (size_t)row * Kpad + (size_t)(((c & 3) ^ ((row >> 1) & 3)) * 8);
        }
    }

    f32x4 acc[FM][FN];
#pragma unroll
    for (int m = 0; m < FM; ++m)
#pragma unroll
        for (int n = 0; n < FN; ++n) acc[m][n] = (f32x4){0.f, 0.f, 0.f, 0.f};

    auto stage = [&](int buf) {
#pragma unroll
        for (int i = 0; i < CH; ++i) {
            async_copy16(srcp[i], &lds[buf][(size_t)((tid & ~63) + i * NT) * 8]);
            srcp[i] += 32;
        }
    };

    auto compute = [&](int buf) {
        f16x8 af[FM], bf[FN];
#pragma unroll
        for (int m = 0; m < FM; ++m) {
            int row = wr * WM + m * 16 + lrow;
            int p = lslot ^ ((row >> 1) & 3);
            af[m] = *(const f16x8*)&lds[buf][(size_t)(row * 4 + p) * 8];
        }
#pragma unroll
        for (int n = 0; n < FN; ++n) {
            int row = wc * WN + n * 16 + lrow;
            int p = lslot ^ ((row >> 1) & 3);
            bf[n] = *(const f16x8*)&lds[buf][(size_t)(ACH + row * 4 + p) * 8];
        }
#pragma unroll
        for (int m = 0; m < FM; ++m)
#pragma unroll
            for (int n = 0; n < FN; ++n)
                acc[m][n] = __builtin_amdgcn_mfma_f32_16x16x32_f16(af[m], bf[n], acc[m][n], 0, 0, 0);
    };

    const int nsteps = Kpad / 32;
    stage(0);
    for (int s = 0; s < nsteps; ++s) {
        if (s + 1 < nsteps) {
            stage((s + 1) & 1);
            asm volatile("s_waitcnt vmcnt(3)" ::: "memory");
        } else {
            asm volatile("s_waitcnt vmcnt(0)" ::: "memory");
        }
        __builtin_amdgcn_s_barrier();
        compute(s & 1);
        __builtin_amdgcn_s_barrier();
    }

    // ---- epilogue: per-wave LDS bounce -> 16B coalesced C stores ----
    __syncthreads();  // all waves done with staging LDS before reuse
    {
        const int LW = WN + 8;                   // padded row (halfs)
        __half* tile = (__half*)lds + (size_t)w * 16 * LW;
        const int CPR = WN / 8;                  // 16B chunks per row
        const int CHT = (16 * CPR) / 64;         // chunks per lane per m-pass
#pragma unroll
        for (int m = 0; m < FM; ++m) {
            int rb = bm + wr * WM + m * 16;
#pragma unroll
            for (int n = 0; n < FN; ++n)
#pragma unroll
                for (int i = 0; i < 4; ++i)
                    tile[((lane >> 4) * 4 + i) * LW + n * 16 + (lane & 15)] =
                        __float2half(acc[m][n][i]);
            // compiler inserts lgkm waits for the LDS RAW below
#pragma unroll
            for (int c = 0; c < CHT; ++c) {
                int ch = lane + c * 64;
                int r = ch / CPR, cc = ch % CPR;
                uint4 v = *(uint4*)&tile[r * LW + cc * 8];
                int grow = rb + r;
                if (grow < M)
                    *(uint4*)&C[(size_t)grow * BN + wc * WN + cc * 8] = v;
            }
        }
    }
}

// ---- gather aggregation (fp16 features, fp32 accum, 4x unrolled) ----------
// out[d] = bias + dinv[d]^2*xw[d] + sum_p val[p]*xw[col[p]]  (; relu)
template <int F, int LPN, int RELU, typename OutT>
__global__ __launch_bounds__(256) void gatherh(const int* __restrict__ rowptr,
                                               const int2* __restrict__ cv,
                                               const __half* __restrict__ xw,
                                               const float* __restrict__ dinv,
                                               const float* __restrict__ bias,
                                               OutT* __restrict__ out, int N) {
    const int NPB = 256 / LPN;
    int d = blockIdx.x * NPB + threadIdx.x / LPN;
    if (d >= N) return;
    int lane = threadIdx.x % LPN;

    float di = dinv[d];
    float w = di * di;
    uint2 raw = *(const uint2*)(xw + (size_t)d * F + lane * 4);
    float2 u0 = __half22float2(*(__half2*)&raw.x);
    float2 u1 = __half22float2(*(__half2*)&raw.y);
    float a0 = w * u0.x, a1 = w * u0.y, a2 = w * u1.x, a3 = w * u1.y;
    float b0 = 0.f, b1 = 0.f, b2 = 0.f, b3 = 0.f;  // second accum set

    int p = rowptr[d], p1 = rowptr[d + 1];
    for (; p + 4 <= p1; p += 4) {
        int2 e0 = cv[p], e1 = cv[p + 1], e2 = cv[p + 2], e3 = cv[p + 3];
        uint2 r0 = *(const uint2*)(xw + (size_t)e0.x * F + lane * 4);
        uint2 r1 = *(const uint2*)(xw + (size_t)e1.x * F + lane * 4);
        uint2 r2 = *(const uint2*)(xw + (size_t)e2.x * F + lane * 4);
        uint2 r3 = *(const uint2*)(xw + (size_t)e3.x * F + lane * 4);
        float w0 = __int_as_float(e0.y), w1 = __int_as_float(e1.y);
        float w2 = __int_as_float(e2.y), w3 = __int_as_float(e3.y);
        {
            float2 v0 = __half22float2(*(__half2*)&r0.x);
            float2 v1 = __half22float2(*(__half2*)&r0.y);
            a0 = fmaf(w0, v0.x, a0); a1 = fmaf(w0, v0.y, a1);
            a2 = fmaf(w0, v1.x, a2); a3 = fmaf(w0, v1.y, a3);
        }
        {
            float2 v0 = __half22float2(*(__half2*)&r1.x);
            float2 v1 = __half22float2(*(__half2*)&r1.y);
            b0 = fmaf(w1, v0.x, b0); b1 = fmaf(w1, v0.y, b1);
            b2 = fmaf(w1, v1.x, b2); b3 = fmaf(w1, v1.y, b3);
        }
        {
            float2 v0 = __half22float2(*(__half2*)&r2.x);
            float2 v1 = __half22float2(*(__half2*)&r2.y);
            a0 = fmaf(w2, v0.x, a0); a1 = fmaf(w2, v0.y, a1);
            a2 = fmaf(w2, v1.x, a2); a3 = fmaf(w2, v1.y, a3);
        }
        {
            float2 v0 = __half22float2(*(__half2*)&r3.x);
            float2 v1 = __half22float2(*(__half2*)&r3.y);
            b0 = fmaf(w3, v0.x, b0); b1 = fmaf(w3, v0.y, b1);
            b2 = fmaf(w3, v1.x, b2); b3 = fmaf(w3, v1.y, b3);
        }
    }
    for (; p < p1; ++p) {
        int2 e = cv[p];
        float wv = __int_as_float(e.y);
        uint2 rv = *(const uint2*)(xw + (size_t)e.x * F + lane * 4);
        float2 v0 = __half22float2(*(__half2*)&rv.x);
        float2 v1 = __half22float2(*(__half2*)&rv.y);
        a0 = fmaf(wv, v0.x, a0); a1 = fmaf(wv, v0.y, a1);
        a2 = fmaf(wv, v1.x, a2); a3 = fmaf(wv, v1.y, a3);
    }
    a0 += b0; a1 += b1; a2 += b2; a3 += b3;

    float4 bb = *(const float4*)&bias[lane * 4];
    a0 += bb.x; a1 += bb.y; a2 += bb.z; a3 += bb.w;
    if (RELU) {
        a0 = fmaxf(a0, 0.f); a1 = fmaxf(a1, 0.f);
        a2 = fmaxf(a2, 0.f); a3 = fmaxf(a3, 0.f);
    }
    if constexpr (std::is_same_v<OutT, float>) {
        *(float4*)&out[(size_t)d * F + lane * 4] = make_float4(a0, a1, a2, a3);
    } else {
        __half2 h0 = __floats2half2_rn(a0, a1);
        __half2 h1 = __floats2half2_rn(a2, a3);
        uint2 packed;
        packed.x = *(uint*)&h0;
        packed.y = *(uint*)&h1;
        *(uint2*)&out[(size_t)d * F + lane * 4] = packed;
    }
}

extern "C" void kernel_launch(void* const* d_in, const int* in_sizes, int n_in,
                              void* d_out, int out_size, void* d_ws, size_t ws_size,
                              hipStream_t stream) {
    const float* x  = (const float*)d_in[0];
    const int*   ei = (const int*)d_in[1];
    const float* ew = (const float*)d_in[2];
    const float* W1 = (const float*)d_in[3];
    const float* b1 = (const float*)d_in[4];
    const float* W2 = (const float*)d_in[5];
    const float* b2 = (const float*)d_in[6];
    float* out = (float*)d_out;

    const int H    = in_sizes[4];            // 256
    const int Fout = in_sizes[6];            // 64
    const int Fin  = in_sizes[3] / H;        // 394
    const int N    = in_sizes[0] / Fin;      // 100000
    const int E    = in_sizes[2];            // 1600000

    const int Kpad1 = (Fin + 31) / 32 * 32;  // 416
    const int Kpad2 = (H + 31) / 32 * 32;    // 256

    const int* src = ei;
    const int* dst = ei + E;

    // workspace layout (all sections 16B aligned)
    unsigned long long* packed = (unsigned long long*)d_ws;  // N
    float* dinv   = (float*)(packed + N);         // N
    int*   rowptr = (int*)(dinv + N);             // N+4
    int*   cursor = rowptr + N + 4;               // N+4
    int*   bsums  = cursor + N + 4;               // 256
    int2*  cv     = (int2*)(bsums + 256);         // E int2 (col,val)
    __half* bufA  = (__half*)(cv + E);            // N*H (xw1, later xw2)
    __half* bufB  = bufA + (size_t)N * H;         // N*H (h)
    __half* xh    = bufB + (size_t)N * H;         // N*Kpad1
    __half* wt1   = xh + (size_t)N * Kpad1;       // H*Kpad1
    __half* wt2   = wt1 + (size_t)H * Kpad1;      // Fout*Kpad2

    const int NB = (N + SCAN_TILE - 1) / SCAN_TILE;

    // 1. degrees + histogram: ONE packed 64-bit atomic per edge
    init_node<<<(N + 255) / 256, 256, 0, stream>>>(packed, N);
    accum_deg_hist<<<(E + 255) / 256, 256, 0, stream>>>(dst, ew, packed, E);

    // 2. CSR build (dinv fused into scan1; cursor-based fill)
    scan1<<<NB, 256, 0, stream>>>(packed, rowptr, dinv, bsums, N);
    scan2<<<1, 256, 0, stream>>>(bsums, rowptr, NB, N, E);
    scan3<<<NB, 256, 0, stream>>>(rowptr, cursor, bsums, N);
    fill_csr<<<(E + 255) / 256, 256, 0, stream>>>(src, dst, ew, dinv, cursor, cv, E);

    // 3. fp16 conversions
    tohalf_w<<<(H * Kpad1 + 255) / 256, 256, 0, stream>>>(W1, wt1, Fin, H, Kpad1);
    tohalf_w<<<(Fout * Kpad2 + 255) / 256, 256, 0, stream>>>(W2, wt2, H, Fout, Kpad2);
    tohalf_x<<<((size_t)N * (Kpad1 / 8) + 255) / 256, 256, 0, stream>>>(x, xh, N, Fin, Kpad1);

    // 4. xw1 = x @ W1   [N,394]@[394,256] -> fp16
    gemm_f16<128, 256, 2, 4, 512><<<(N + 127) / 128, 512, 0, stream>>>(xh, wt1, bufA, N, Kpad1);

    // 5. h = relu(gather + bias) -> fp16
    gatherh<256, 64, 1, __half><<<(N + 3) / 4, 256, 0, stream>>>(
        rowptr, cv, bufA, dinv, b1, bufB, N);

    // 6. xw2 = h @ W2   [N,256]@[256,64] -> fp16
    gemm_f16<128, 64, 2, 2, 256><<<(N + 127) / 128, 256, 0, stream>>>(bufB, wt2, bufA, N, Kpad2);

    // 7. out = gather + bias -> fp32
    gatherh<64, 16, 0, float><<<(N + 15) / 16, 256, 0, stream>>>(
        rowptr, cv, bufA, dinv, b2, out, N);
}

// Round 13
// 466.770 us; speedup vs baseline: 1.1923x; 1.0203x over previous
//
#include <hip/hip_runtime.h>
#include <hip/hip_bf16.h>
#include <hip/hip_fp16.h>
#include <type_traits>

// ---------------------------------------------------------------------------
// 2-layer GCN. CSR-gather aggregation (fp16 features, fp32 accum, 4x-unrolled
// edge loop). (col,val) packed int2. Preprocessing: ONE 64-bit packed atomic
// per edge; dinv fused into scan1; cursor-based CSR fill.
// GEMM1: fp32 A loaded directly (fused convert in staging, T14 issue-early,
// 1 barrier/step). GEMM2: fp16 A via global_load_lds (counted vmcnt(3)).
// Both: fp16 MFMA fp32-accum, double-buffered LDS, LDS-bounce epilogue.
// ---------------------------------------------------------------------------

typedef _Float16 f16x8 __attribute__((ext_vector_type(8)));
typedef float f32x4 __attribute__((ext_vector_type(4)));

#define DEG_MASK ((1ull << 42) - 1)

__device__ inline void async_copy16(const void* g, void* l) {
    __builtin_amdgcn_global_load_lds(
        (const __attribute__((address_space(1))) void*)g,
        (__attribute__((address_space(3))) void*)l, 16, 0, 0);
}

// ------------------------- graph preprocessing -----------------------------
// packed[i]: bits [63:42] = edge count, bits [41:0] = sum(ew) in 2^-32 fixed pt

__global__ __launch_bounds__(256) void init_node(unsigned long long* packed, int N) {
    int i = blockIdx.x * 256 + threadIdx.x;
    if (i < N) packed[i] = 0ull;
}

__global__ __launch_bounds__(256) void accum_deg_hist(const int* __restrict__ dst,
                                                      const float* __restrict__ ew,
                                                      unsigned long long* packed, int E) {
    int e = blockIdx.x * 256 + threadIdx.x;
    if (e < E) {
        int d = dst[e];
        unsigned long long add =
            (1ull << 42) + (unsigned long long)(ew[e] * 4294967296.0f);
        atomicAdd(&packed[d], add);
    }
}

#define SCAN_TILE 2048

// exclusive scan of counts; also computes dinv = rsqrt(1 + deg) per node
__global__ __launch_bounds__(256) void scan1(const unsigned long long* __restrict__ packed,
                                             int* __restrict__ rowptr,
                                             float* __restrict__ dinv,
                                             int* __restrict__ bsums, int N) {
    __shared__ int tmp[256];
    int t = threadIdx.x;
    int base = blockIdx.x * SCAN_TILE + t * 8;
    int v[8], s = 0;
#pragma unroll
    for (int j = 0; j < 8; ++j) {
        int idx = base + j;
        if (idx < N) {
            unsigned long long pv = packed[idx];
            v[j] = (int)(pv >> 42);
            dinv[idx] = rsqrtf(1.0f + (float)(pv & DEG_MASK) * (1.0f / 4294967296.0f));
        } else v[j] = 0;
        s += v[j];
    }
    tmp[t] = s;
    __syncthreads();
#pragma unroll
    for (int off = 1; off < 256; off <<= 1) {
        int u = (t >= off) ? tmp[t - off] : 0;
        __syncthreads();
        tmp[t] += u;
        __syncthreads();
    }
    int run = tmp[t] - s;
#pragma unroll
    for (int j = 0; j < 8; ++j) {
        if (base + j < N) rowptr[base + j] = run;
        run += v[j];
    }
    if (t == 255) bsums[blockIdx.x] = tmp[255];
}

__global__ __launch_bounds__(256) void scan2(int* bsums, int* rowptr, int NB, int N, int E) {
    __shared__ int tmp[256];
    int t = threadIdx.x;
    int v = (t < NB) ? bsums[t] : 0;
    tmp[t] = v;
    __syncthreads();
#pragma unroll
    for (int off = 1; off < 256; off <<= 1) {
        int u = (t >= off) ? tmp[t - off] : 0;
        __syncthreads();
        tmp[t] += u;
        __syncthreads();
    }
    if (t < NB) bsums[t] = tmp[t] - v;
    if (t == 0) rowptr[N] = E;
}

// writes final rowptr AND initializes cursor = rowptr
__global__ __launch_bounds__(256) void scan3(int* rowptr, int* cursor,
                                             const int* __restrict__ bsums, int N) {
    int base = blockIdx.x * SCAN_TILE + threadIdx.x * 8;
    int off = bsums[blockIdx.x];
#pragma unroll
    for (int j = 0; j < 8; ++j)
        if (base + j < N) {
            int v = rowptr[base + j] + off;
            rowptr[base + j] = v;
            cursor[base + j] = v;
        }
}

// single atomic per edge; (col,val) packed as one 8B store
__global__ __launch_bounds__(256) void fill_csr(const int* __restrict__ src,
                                                const int* __restrict__ dst,
                                                const float* __restrict__ ew,
                                                const float* __restrict__ dinv,
                                                int* __restrict__ cursor,
                                                int2* __restrict__ cv, int E) {
    int e = blockIdx.x * 256 + threadIdx.x;
    if (e < E) {
        int d = dst[e], s = src[e];
        int pos = atomicAdd(&cursor[d], 1);
        float v = dinv[s] * ew[e] * dinv[d];
        cv[pos] = make_int2(s, __float_as_int(v));
    }
}

// --------- W[K][N] fp32 -> fp16 transposed [N][Kpad] (zero-padded K) -------
__global__ __launch_bounds__(256) void tohalf_w(const float* __restrict__ W,
                                                __half* __restrict__ WT,
                                                int K, int N, int Kpad) {
    int idx = blockIdx.x * 256 + threadIdx.x;
    int total = N * Kpad;
    if (idx >= total) return;
    int n = idx / Kpad, k = idx % Kpad;
    float v = (k < K) ? W[(size_t)k * N + n] : 0.0f;
    WT[idx] = __float2half(v);
}

// ------- GEMM1: C[M,BN](fp16) = A[M,K](fp32) @ BT^T, fused A-convert -------
// A-staging: 4x float2 loads -> cvt -> ds_write_b128; B via global_load_lds.
// Issue-early: loads for s+1 before compute(s); vmcnt(2) = A landed (FIFO),
// then convert+write; vmcnt(0)+lgkmcnt(0); ONE barrier per step.
template <int BM, int BN, int WARPS_M, int WARPS_N, int NT>
__global__ __launch_bounds__(NT) void gemm_f32a(const float* __restrict__ Ax,
                                                const __half* __restrict__ BT,
                                                __half* __restrict__ C,
                                                int M, int K, int Kpad) {
    const int WM = BM / WARPS_M, WN = BN / WARPS_N;
    const int FM = WM / 16, FN = WN / 16;
    const int ACH = BM * 4;              // A chunks (8 halfs each)
    const int BCH = BN * 4;              // B chunks
    static_assert(ACH == NT, "1 A-chunk per thread");
    static_assert(BCH == 2 * NT, "2 B-chunks per thread");
    __shared__ __align__(16) __half lds[2][(ACH + BCH) * 8];

    int tid = threadIdx.x;
    int lane = tid & 63;
    int w = tid >> 6;
    int wr = w / WARPS_N, wc = w % WARPS_N;
    int bm = blockIdx.x * BM;
    int lrow = lane & 15;
    int lslot = lane >> 4;

    // A chunk geometry (1 per thread)
    int arow = tid >> 2, ap = tid & 3;
    int aslot = ap ^ ((arow >> 1) & 3);
    int agrow = bm + arow; if (agrow >= M) agrow = M - 1;
    const float* abase = Ax + (size_t)agrow * K;

    // B source pointers (2 per thread)
    const __half* bsrc[2];
#pragma unroll
    for (int i = 0; i < 2; ++i) {
        int c = tid + i * NT;            // B-chunk index in [0, BCH)
        int row = c >> 2, p = c & 3;
        bsrc[i] = BT + (size_t)row * Kpad + (size_t)((p ^ ((row >> 1) & 3)) * 8);
    }

    f32x4 acc[FM][FN];
#pragma unroll
    for (int m = 0; m < FM; ++m)
#pragma unroll
        for (int n = 0; n < FN; ++n) acc[m][n] = (f32x4){0.f, 0.f, 0.f, 0.f};

    float2 ar[4];
    auto loadA = [&](int s) {
        int gk = s * 32 + aslot * 8;
        if (gk + 8 <= K) {
            const float* p = abase + gk;  // 8B-aligned always (gk even, row 8B)
            ar[0] = *(const float2*)p;
            ar[1] = *(const float2*)(p + 2);
            ar[2] = *(const float2*)(p + 4);
            ar[3] = *(const float2*)(p + 6);
        } else {
            float t[8];
#pragma unroll
            for (int j = 0; j < 8; ++j) t[j] = (gk + j < K) ? abase[gk + j] : 0.0f;
            ar[0] = make_float2(t[0], t[1]);
            ar[1] = make_float2(t[2], t[3]);
            ar[2] = make_float2(t[4], t[5]);
            ar[3] = make_float2(t[6], t[7]);
        }
    };
    auto writeA = [&](int buf) {
        union { __half2 h[4]; uint4 u; } pk;
#pragma unroll
        for (int j = 0; j < 4; ++j) pk.h[j] = __floats2half2_rn(ar[j].x, ar[j].y);
        *(uint4*)&lds[buf][(size_t)tid * 8] = pk.u;
    };
    auto stageB = [&](int buf) {
#pragma unroll
        for (int i = 0; i < 2; ++i) {
            async_copy16(bsrc[i], &lds[buf][(size_t)((tid & ~63) + (i + 1) * NT) * 8]);
            bsrc[i] += 32;
        }
    };

    auto compute = [&](int buf) {
        f16x8 af[FM], bf[FN];
#pragma unroll
        for (int m = 0; m < FM; ++m) {
            int row = wr * WM + m * 16 + lrow;
            int p = lslot ^ ((row >> 1) & 3);
            af[m] = *(const f16x8*)&lds[buf][(size_t)(row * 4 + p) * 8];
        }
#pragma unroll
        for (int n = 0; n < FN; ++n) {
            int row = wc * WN + n * 16 + lrow;
            int p = lslot ^ ((row >> 1) & 3);
            bf[n] = *(const f16x8*)&lds[buf][(size_t)(ACH + row * 4 + p) * 8];
        }
#pragma unroll
        for (int m = 0; m < FM; ++m)
#pragma unroll
            for (int n = 0; n < FN; ++n)
                acc[m][n] = __builtin_amdgcn_mfma_f32_16x16x32_f16(af[m], bf[n], acc[m][n], 0, 0, 0);
    };

    const int nsteps = Kpad / 32;
    // prologue: fill buf 0
    loadA(0);                            // 4 loads issued first (oldest)
    stageB(0);                           // 2 DMAs after
    asm volatile("s_waitcnt vmcnt(2)" ::: "memory");   // A regs landed
    writeA(0);
    asm volatile("s_waitcnt vmcnt(0) lgkmcnt(0)" ::: "memory");
    __builtin_amdgcn_s_barrier();
    for (int s = 0; s < nsteps; ++s) {
        bool more = (s + 1 < nsteps);
        if (more) { loadA(s + 1); stageB((s + 1) & 1); }
        compute(s & 1);
        if (more) {
            asm volatile("s_waitcnt vmcnt(2)" ::: "memory");
            writeA((s + 1) & 1);
            asm volatile("s_waitcnt vmcnt(0) lgkmcnt(0)" ::: "memory");
        }
        __builtin_amdgcn_s_barrier();
    }

    // ---- epilogue: per-wave LDS bounce -> 16B coalesced C stores ----
    __syncthreads();
    {
        const int LW = WN + 8;
        __half* tile = (__half*)lds + (size_t)w * 16 * LW;
        const int CPR = WN / 8;
        const int CHT = (16 * CPR) / 64;
#pragma unroll
        for (int m = 0; m < FM; ++m) {
            int rb = bm + wr * WM + m * 16;
#pragma unroll
            for (int n = 0; n < FN; ++n)
#pragma unroll
                for (int i = 0; i < 4; ++i)
                    tile[((lane >> 4) * 4 + i) * LW + n * 16 + (lane & 15)] =
                        __float2half(acc[m][n][i]);
#pragma unroll
            for (int c = 0; c < CHT; ++c) {
                int ch = lane + c * 64;
                int r = ch / CPR, cc = ch % CPR;
                uint4 v = *(uint4*)&tile[r * LW + cc * 8];
                int grow = rb + r;
                if (grow < M)
                    *(uint4*)&C[(size_t)grow * BN + wc * WN + cc * 8] = v;
            }
        }
    }
}

// ---------------- GEMM2: fp16 A, all-global_load_lds staging ---------------
template <int BM, int BN, int WARPS_M, int WARPS_N, int NT>
__global__ __launch_bounds__(NT) void gemm_f16(const __half* __restrict__ Ah,
                                               const __half* __restrict__ BT,
                                               __half* __restrict__ C,
                                               int M, int Kpad) {
    const int WM = BM / WARPS_M, WN = BN / WARPS_N;
    const int FM = WM / 16, FN = WN / 16;
    const int ACH = BM * 4;
    const int BCH = BN * 4;
    const int TOTCH = ACH + BCH;
    const int CH = TOTCH / NT;
    static_assert(CH == 3, "vmcnt(3) hardcoded below");
    __shared__ __align__(16) __half lds[2][TOTCH * 8];

    int tid = threadIdx.x;
    int lane = tid & 63;
    int w = tid >> 6;
    int wr = w / WARPS_N, wc = w % WARPS_N;
    int bm = blockIdx.x * BM;
    int lrow = lane & 15;
    int lslot = lane >> 4;

    const __half* srcp[CH];
#pragma unroll
    for (int i = 0; i < CH; ++i) {
        int ch = tid + i * NT;
        if (ch < ACH) {
            int c = ch, row = c >> 2;
            int grow = bm + row;
            if (grow >= M) grow = M - 1;
            srcp[i] = Ah + (size_t)grow * Kpad + (size_t)(((c & 3) ^ ((row >> 1) & 3)) * 8);
        } else {
            int c = ch - ACH, row = c >> 2;
            srcp[i] = BT + (size_t)row * Kpad + (size_t)(((c & 3) ^ ((row >> 1) & 3)) * 8);
        }
    }

    f32x4 acc[FM][FN];
#pragma unroll
    for (int m = 0; m < FM; ++m)
#pragma unroll
        for (int n = 0; n < FN; ++n) acc[m][n] = (f32x4){0.f, 0.f, 0.f, 0.f};

    auto stage = [&](int buf) {
#pragma unroll
        for (int i = 0; i < CH; ++i) {
            async_copy16(srcp[i], &lds[buf][(size_t)((tid & ~63) + i * NT) * 8]);
            srcp[i] += 32;
        }
    };

    auto compute = [&](int buf) {
        f16x8 af[FM], bf[FN];
#pragma unroll
        for (int m = 0; m < FM; ++m) {
            int row = wr * WM + m * 16 + lrow;
            int p = lslot ^ ((row >> 1) & 3);
            af[m] = *(const f16x8*)&lds[buf][(size_t)(row * 4 + p) * 8];
        }
#pragma unroll
        for (int n = 0; n < FN; ++n) {
            int row = wc * WN + n * 16 + lrow;
            int p = lslot ^ ((row >> 1) & 3);
            bf[n] = *(const f16x8*)&lds[buf][(size_t)(ACH + row * 4 + p) * 8];
        }
#pragma unroll
        for (int m = 0; m < FM; ++m)
#pragma unroll
            for (int n = 0; n < FN; ++n)
                acc[m][n] = __builtin_amdgcn_mfma_f32_16x16x32_f16(af[m], bf[n], acc[m][n], 0, 0, 0);
    };

    const int nsteps = Kpad / 32;
    stage(0);
    for (int s = 0; s < nsteps; ++s) {
        if (s + 1 < nsteps) {
            stage((s + 1) & 1);
            asm volatile("s_waitcnt vmcnt(3)" ::: "memory");
        } else {
            asm volatile("s_waitcnt vmcnt(0)" ::: "memory");
        }
        __builtin_amdgcn_s_barrier();
        compute(s & 1);
        __builtin_amdgcn_s_barrier();
    }

    __syncthreads();
    {
        const int LW = WN + 8;
        __half* tile = (__half*)lds + (size_t)w * 16 * LW;
        const int CPR = WN / 8;
        const int CHT = (16 * CPR) / 64;
#pragma unroll
        for (int m = 0; m < FM; ++m) {
            int rb = bm + wr * WM + m * 16;
#pragma unroll
            for (int n = 0; n < FN; ++n)
#pragma unroll
                for (int i = 0; i < 4; ++i)
                    tile[((lane >> 4) * 4 + i) * LW + n * 16 + (lane & 15)] =
                        __float2half(acc[m][n][i]);
#pragma unroll
            for (int c = 0; c < CHT; ++c) {
                int ch = lane + c * 64;
                int r = ch / CPR, cc = ch % CPR;
                uint4 v = *(uint4*)&tile[r * LW + cc * 8];
                int grow = rb + r;
                if (grow < M)
                    *(uint4*)&C[(size_t)grow * BN + wc * WN + cc * 8] = v;
            }
        }
    }
}

// ---- gather aggregation (fp16 features, fp32 accum, 4x unrolled) ----------
template <int F, int LPN, int RELU, typename OutT>
__global__ __launch_bounds__(256) void gatherh(const int* __restrict__ rowptr,
                                               const int2* __restrict__ cv,
                                               const __half* __restrict__ xw,
                                               const float* __restrict__ dinv,
                                               const float* __restrict__ bias,
                                               OutT* __restrict__ out, int N) {
    const int NPB = 256 / LPN;
    int d = blockIdx.x * NPB + threadIdx.x / LPN;
    if (d >= N) return;
    int lane = threadIdx.x % LPN;

    float di = dinv[d];
    float w = di * di;
    uint2 raw = *(const uint2*)(xw + (size_t)d * F + lane * 4);
    float2 u0 = __half22float2(*(__half2*)&raw.x);
    float2 u1 = __half22float2(*(__half2*)&raw.y);
    float a0 = w * u0.x, a1 = w * u0.y, a2 = w * u1.x, a3 = w * u1.y;
    float b0 = 0.f, b1 = 0.f, b2 = 0.f, b3 = 0.f;

    int p = rowptr[d], p1 = rowptr[d + 1];
    for (; p + 4 <= p1; p += 4) {
        int2 e0 = cv[p], e1 = cv[p + 1], e2 = cv[p + 2], e3 = cv[p + 3];
        uint2 r0 = *(const uint2*)(xw + (size_t)e0.x * F + lane * 4);
        uint2 r1 = *(const uint2*)(xw + (size_t)e1.x * F + lane * 4);
        uint2 r2 = *(const uint2*)(xw + (size_t)e2.x * F + lane * 4);
        uint2 r3 = *(const uint2*)(xw + (size_t)e3.x * F + lane * 4);
        float w0 = __int_as_float(e0.y), w1 = __int_as_float(e1.y);
        float w2 = __int_as_float(e2.y), w3 = __int_as_float(e3.y);
        {
            float2 v0 = __half22float2(*(__half2*)&r0.x);
            float2 v1 = __half22float2(*(__half2*)&r0.y);
            a0 = fmaf(w0, v0.x, a0); a1 = fmaf(w0, v0.y, a1);
            a2 = fmaf(w0, v1.x, a2); a3 = fmaf(w0, v1.y, a3);
        }
        {
            float2 v0 = __half22float2(*(__half2*)&r1.x);
            float2 v1 = __half22float2(*(__half2*)&r1.y);
            b0 = fmaf(w1, v0.x, b0); b1 = fmaf(w1, v0.y, b1);
            b2 = fmaf(w1, v1.x, b2); b3 = fmaf(w1, v1.y, b3);
        }
        {
            float2 v0 = __half22float2(*(__half2*)&r2.x);
            float2 v1 = __half22float2(*(__half2*)&r2.y);
            a0 = fmaf(w2, v0.x, a0); a1 = fmaf(w2, v0.y, a1);
            a2 = fmaf(w2, v1.x, a2); a3 = fmaf(w2, v1.y, a3);
        }
        {
            float2 v0 = __half22float2(*(__half2*)&r3.x);
            float2 v1 = __half22float2(*(__half2*)&r3.y);
            b0 = fmaf(w3, v0.x, b0); b1 = fmaf(w3, v0.y, b1);
            b2 = fmaf(w3, v1.x, b2); b3 = fmaf(w3, v1.y, b3);
        }
    }
    for (; p < p1; ++p) {
        int2 e = cv[p];
        float wv = __int_as_float(e.y);
        uint2 rv = *(const uint2*)(xw + (size_t)e.x * F + lane * 4);
        float2 v0 = __half22float2(*(__half2*)&rv.x);
        float2 v1 = __half22float2(*(__half2*)&rv.y);
        a0 = fmaf(wv, v0.x, a0); a1 = fmaf(wv, v0.y, a1);
        a2 = fmaf(wv, v1.x, a2); a3 = fmaf(wv, v1.y, a3);
    }
    a0 += b0; a1 += b1; a2 += b2; a3 += b3;

    float4 bb = *(const float4*)&bias[lane * 4];
    a0 += bb.x; a1 += bb.y; a2 += bb.z; a3 += bb.w;
    if (RELU) {
        a0 = fmaxf(a0, 0.f); a1 = fmaxf(a1, 0.f);
        a2 = fmaxf(a2, 0.f); a3 = fmaxf(a3, 0.f);
    }
    if constexpr (std::is_same_v<OutT, float>) {
        *(float4*)&out[(size_t)d * F + lane * 4] = make_float4(a0, a1, a2, a3);
    } else {
        __half2 h0 = __floats2half2_rn(a0, a1);
        __half2 h1 = __floats2half2_rn(a2, a3);
        uint2 packed;
        packed.x = *(uint*)&h0;
        packed.y = *(uint*)&h1;
        *(uint2*)&out[(size_t)d * F + lane * 4] = packed;
    }
}

extern "C" void kernel_launch(void* const* d_in, const int* in_sizes, int n_in,
                              void* d_out, int out_size, void* d_ws, size_t ws_size,
                              hipStream_t stream) {
    const float* x  = (const float*)d_in[0];
    const int*   ei = (const int*)d_in[1];
    const float* ew = (const float*)d_in[2];
    const float* W1 = (const float*)d_in[3];
    const float* b1 = (const float*)d_in[4];
    const float* W2 = (const float*)d_in[5];
    const float* b2 = (const float*)d_in[6];
    float* out = (float*)d_out;

    const int H    = in_sizes[4];            // 256
    const int Fout = in_sizes[6];            // 64
    const int Fin  = in_sizes[3] / H;        // 394
    const int N    = in_sizes[0] / Fin;      // 100000
    const int E    = in_sizes[2];            // 1600000

    const int Kpad1 = (Fin + 31) / 32 * 32;  // 416
    const int Kpad2 = (H + 31) / 32 * 32;    // 256

    const int* src = ei;
    const int* dst = ei + E;

    // workspace layout (all sections 16B aligned)
    unsigned long long* packed = (unsigned long long*)d_ws;  // N
    float* dinv   = (float*)(packed + N);         // N
    int*   rowptr = (int*)(dinv + N);             // N+4
    int*   cursor = rowptr + N + 4;               // N+4
    int*   bsums  = cursor + N + 4;               // 256
    int2*  cv     = (int2*)(bsums + 256);         // E int2 (col,val)
    __half* bufA  = (__half*)(cv + E);            // N*H (xw1, later xw2)
    __half* bufB  = bufA + (size_t)N * H;         // N*H (h)
    __half* wt1   = bufB + (size_t)N * H;         // H*Kpad1
    __half* wt2   = wt1 + (size_t)H * Kpad1;      // Fout*Kpad2

    const int NB = (N + SCAN_TILE - 1) / SCAN_TILE;

    // 1. degrees + histogram: ONE packed 64-bit atomic per edge
    init_node<<<(N + 255) / 256, 256, 0, stream>>>(packed, N);
    accum_deg_hist<<<(E + 255) / 256, 256, 0, stream>>>(dst, ew, packed, E);

    // 2. CSR build (dinv fused into scan1; cursor-based fill)
    scan1<<<NB, 256, 0, stream>>>(packed, rowptr, dinv, bsums, N);
    scan2<<<1, 256, 0, stream>>>(bsums, rowptr, NB, N, E);
    scan3<<<NB, 256, 0, stream>>>(rowptr, cursor, bsums, N);
    fill_csr<<<(E + 255) / 256, 256, 0, stream>>>(src, dst, ew, dinv, cursor, cv, E);

    // 3. weight conversions (x conversion fused into GEMM1)
    tohalf_w<<<(H * Kpad1 + 255) / 256, 256, 0, stream>>>(W1, wt1, Fin, H, Kpad1);
    tohalf_w<<<(Fout * Kpad2 + 255) / 256, 256, 0, stream>>>(W2, wt2, H, Fout, Kpad2);

    // 4. xw1 = x @ W1   [N,394](fp32)@[394,256] -> fp16 (fused A convert)
    gemm_f32a<128, 256, 2, 4, 512><<<(N + 127) / 128, 512, 0, stream>>>(
        x, wt1, bufA, N, Fin, Kpad1);

    // 5. h = relu(gather + bias) -> fp16
    gatherh<256, 64, 1, __half><<<(N + 3) / 4, 256, 0, stream>>>(
        rowptr, cv, bufA, dinv, b1, bufB, N);

    // 6. xw2 = h @ W2   [N,256]@[256,64] -> fp16
    gemm_f16<128, 64, 2, 2, 256><<<(N + 127) / 128, 256, 0, stream>>>(bufB, wt2, bufA, N, Kpad2);

    // 7. out = gather + bias -> fp32
    gatherh<64, 16, 0, float><<<(N + 15) / 16, 256, 0, stream>>>(
        rowptr, cv, bufA, dinv, b2, out, N);
}